// Round 10
// baseline (758.381 us; speedup 1.0000x reference)
//
#include <hip/hip_runtime.h>

#define B_ROWS 8192
#define WIDTH  512
#define DEPTH  7
#define CIN    4096
#define EPS    1e-5f
#define SLOPE  0.01f

typedef __attribute__((ext_vector_type(8))) short short8;
typedef __attribute__((ext_vector_type(4))) short short4v;
typedef __attribute__((ext_vector_type(4))) float f32x4;
typedef __attribute__((ext_vector_type(16))) float f32x16;

// round-to-nearest-even f32 -> bf16 bits
__device__ inline short f2bf(float f) {
  unsigned u = __builtin_bit_cast(unsigned, f);
  unsigned r = (u + 0x7FFFu + ((u >> 16) & 1u)) >> 16;
  return (short)r;
}

__device__ inline void gl_lds16(const void* g, void* l) {
  __builtin_amdgcn_global_load_lds(
      (const __attribute__((address_space(1))) unsigned*)g,
      (__attribute__((address_space(3))) unsigned*)l, 16, 0, 0);
}

// grid-wide barrier (cooperative-groups grid.sync pattern). SAFETY: grid=512,
// LDS 48KB => <=3 blocks/CU, launch_bounds(256,2) => VGPR<=256 => >=2 blocks/CU;
// capacity 512..768 >= 512 => all blocks co-resident => no deadlock.
__device__ inline void gridbar(unsigned* ctr, unsigned target) {
  __threadfence();
  __syncthreads();
  if (threadIdx.x == 0) {
    __hip_atomic_fetch_add(ctr, 1u, __ATOMIC_ACQ_REL, __HIP_MEMORY_SCOPE_AGENT);
    while (__hip_atomic_load(ctr, __ATOMIC_ACQUIRE, __HIP_MEMORY_SCOPE_AGENT) < target) {
      __builtin_amdgcn_s_sleep(2);
    }
  }
  __syncthreads();
}

// ------- merged prologue: convw + initx + zero sums/counters ------------------
struct WP { const float* p[7]; };

__global__ __launch_bounds__(256) void prolog(WP wp, short* __restrict__ wbf,
                                              const float* __restrict__ x,
                                              const float* __restrict__ wc,
                                              short* __restrict__ lastbf,
                                              float* __restrict__ logit,
                                              float* __restrict__ sumsz,
                                              unsigned* __restrict__ ctr) {
  if (blockIdx.x >= 2048) {
    long e = ((long)(blockIdx.x - 2048) * 256 + threadIdx.x) * 4;
    int layer; long base;
    if      (e < 262144L)  { layer = 0; base = 0; }
    else if (e < 786432L)  { layer = 1; base = 262144L; }
    else if (e < 1572864L) { layer = 2; base = 786432L; }
    else if (e < 2621440L) { layer = 3; base = 1572864L; }
    else if (e < 3932160L) { layer = 4; base = 2621440L; }
    else if (e < 5505024L) { layer = 5; base = 3932160L; }
    else                   { layer = 6; base = 5505024L; }
    f32x4 v = *(const f32x4*)(wp.p[layer] + (e - base));
    short4v o;
    o.x = f2bf(v.x); o.y = f2bf(v.y); o.z = f2bf(v.z); o.w = f2bf(v.w);
    *(short4v*)(wbf + e) = o;
    return;
  }
  int gid = blockIdx.x * 256 + threadIdx.x;
  if (gid < DEPTH * 1024) sumsz[gid] = 0.f;  // zero all layers' stats buffers
  if (gid < 8) ctr[gid] = 0u;                // zero grid-barrier counters
  int w = threadIdx.x >> 6, l = threadIdx.x & 63;
  int r = blockIdx.x * 4 + w;
  const float* xr = x + (long)r * 512 + l * 8;
  f32x4 v0 = *(const f32x4*)xr;
  f32x4 v1 = *(const f32x4*)(xr + 4);
  const float* wcr = wc + l * 8;
  float acc = 0.f;
  short8 ob;
#pragma unroll
  for (int j = 0; j < 4; ++j) { acc += v0[j] * wcr[j];     ob[j]     = f2bf(v0[j]); }
#pragma unroll
  for (int j = 0; j < 4; ++j) { acc += v1[j] * wcr[4 + j]; ob[4 + j] = f2bf(v1[j]); }
  *(short8*)&lastbf[(long)r * CIN + l * 8] = ob;
#pragma unroll
  for (int off = 32; off; off >>= 1) acc += __shfl_xor(acc, off);
  if (l == 0) logit[r] = acc;
}

// -------- fused layer: bf16 MFMA GEMM + stats + gridbar + BN epilogue ---------
// GEMM part is the proven R8 structure verbatim: BM=128, BN=64, BK=64,
// grid (64,8)=512 blocks, 4 waves (wave ks = K-quarter, full 128x64 tile,
// 32x32x16 MFMA, acc[4][2] f32x16), dbuf LDS (As 16KB + Bs 8KB)x2,
// XOR-swizzle byte^((row&7)<<4) via pre-swizzled global source.
// Epilogue: combine K-quarters into Red (full tile), atomicAdd column stats,
// prefetch noise, grid barrier, then BN+LeakyReLU+noise+classifier-partial
// and bf16 store straight into the concat buffer. No hpre, no bnact kernel.
__global__ __launch_bounds__(256, 2) void layer_fused(
    const short* __restrict__ A, const short* __restrict__ Bw,
    float* __restrict__ sums, const float* __restrict__ gamma,
    const float* __restrict__ beta, const float* __restrict__ noise,
    const float* __restrict__ wc, short* __restrict__ lastseg,
    float* __restrict__ logit, unsigned* __restrict__ ctr, int K) {
  __shared__ __align__(16) char smem[49152];  // 2 x (As 16KB + Bs 8KB)
  int t = threadIdx.x;
  int ks = t >> 6, l = t & 63;
  int l31 = l & 31, hi = l >> 5;
  int bm = blockIdx.x, bn = blockIdx.y;
  const short* Ab = A + (long)(bm * 128) * CIN;
  const short* Bb = Bw + (long)(bn * 64) * K;

  f32x16 acc[4][2];
#pragma unroll
  for (int m = 0; m < 4; ++m)
#pragma unroll
    for (int n = 0; n < 2; ++n)
#pragma unroll
      for (int r = 0; r < 16; ++r) acc[m][n][r] = 0.f;

  int l8 = l >> 3;
  int scol = ((l & 7) ^ l8) << 3;  // pre-swizzled source col (16B chunk)

#define STAGE(buf, k0)                                                                       \
  {                                                                                          \
    char* base = smem + (buf) * 24576;                                                       \
    int c0 = ks * 4, c1 = ks * 2;                                                            \
    gl_lds16(Ab + (long)((c0    ) * 8 + l8) * CIN + (k0) + scol, base + (c0    ) * 1024);    \
    gl_lds16(Ab + (long)((c0 + 1) * 8 + l8) * CIN + (k0) + scol, base + (c0 + 1) * 1024);    \
    gl_lds16(Ab + (long)((c0 + 2) * 8 + l8) * CIN + (k0) + scol, base + (c0 + 2) * 1024);    \
    gl_lds16(Ab + (long)((c0 + 3) * 8 + l8) * CIN + (k0) + scol, base + (c0 + 3) * 1024);    \
    gl_lds16(Bb + (long)((c1    ) * 8 + l8) * K + (k0) + scol, base + 16384 + (c1    ) * 1024); \
    gl_lds16(Bb + (long)((c1 + 1) * 8 + l8) * K + (k0) + scol, base + 16384 + (c1 + 1) * 1024); \
  }

  STAGE(0, 0);
  __syncthreads();

  int kb = ks * 32 + hi * 16;
  int sw = (l & 7) << 4;  // row&7 == l&7 since frag rows are m*32 + l31

  int nt = K >> 6;
  int cur = 0;
  for (int tix = 0; tix < nt; ++tix) {
    if (tix + 1 < nt) STAGE(cur ^ 1, (tix + 1) << 6);
    const char* AsC = smem + cur * 24576;
    const char* BsC = AsC + 16384;
    short8 a[4], b[2];
#pragma unroll
    for (int m = 0; m < 4; ++m)
      a[m] = *(const short8*)(AsC + (m * 32 + l31) * 128 + (kb ^ sw));
#pragma unroll
    for (int n = 0; n < 2; ++n)
      b[n] = *(const short8*)(BsC + (n * 32 + l31) * 128 + (kb ^ sw));
#pragma unroll
    for (int m = 0; m < 4; ++m)
#pragma unroll
      for (int n = 0; n < 2; ++n)
        acc[m][n] = __builtin_amdgcn_mfma_f32_32x32x16_bf16(a[m], b[n], acc[m][n], 0, 0, 0);
    __syncthreads();
    cur ^= 1;
  }

  // ---- combine 4 K-quarters into Red (full tile), column stats ----
  float* Red = (float*)smem;  // 128x64 f32 = 32KB
#define RIDX(m, n, r) (((m) * 32 + ((r) & 3) + 8 * ((r) >> 2) + 4 * hi) * 64 + (n) * 32 + l31)
  if (ks == 3) {
#pragma unroll
    for (int m = 0; m < 4; ++m)
#pragma unroll
      for (int n = 0; n < 2; ++n)
#pragma unroll
        for (int r = 0; r < 16; ++r) Red[RIDX(m, n, r)] = acc[m][n][r];
  }
  __syncthreads();
  if (ks == 2) {
#pragma unroll
    for (int m = 0; m < 4; ++m)
#pragma unroll
      for (int n = 0; n < 2; ++n)
#pragma unroll
        for (int r = 0; r < 16; ++r) Red[RIDX(m, n, r)] += acc[m][n][r];
  }
  __syncthreads();
  if (ks == 1) {
#pragma unroll
    for (int m = 0; m < 4; ++m)
#pragma unroll
      for (int n = 0; n < 2; ++n)
#pragma unroll
        for (int r = 0; r < 16; ++r) Red[RIDX(m, n, r)] += acc[m][n][r];
  }
  __syncthreads();
  if (ks == 0) {
#pragma unroll
    for (int n = 0; n < 2; ++n) {
      float s = 0.f, q = 0.f;
#pragma unroll
      for (int m = 0; m < 4; ++m) {
#pragma unroll
        for (int r = 0; r < 16; ++r) {
          float v = acc[m][n][r] + Red[RIDX(m, n, r)];
          Red[RIDX(m, n, r)] = v;
          s += v; q += v * v;
        }
      }
      s += __shfl_xor(s, 32);
      q += __shfl_xor(q, 32);
      if (l < 32) {
        int colg = bn * 64 + n * 32 + l;
        atomicAdd(&sums[colg], s);
        atomicAdd(&sums[WIDTH + colg], q);
      }
    }
  }
#undef RIDX
#undef STAGE

  // ---- prefetch noise for this block's tile (in flight during the spin) ----
  int colL = bn * 64 + l;  // lane's column (0..63 within tile -> global col)
  const float* np = noise + (long)(bm * 128 + ks * 32) * WIDTH + colL;
  float nv[32];
#pragma unroll
  for (int r = 0; r < 32; ++r) nv[r] = np[(long)r * WIDTH];

  // ---- grid barrier: stats complete device-wide ----
  gridbar(ctr, 512u);

  // ---- BN + LeakyReLU + noise + classifier partial + bf16 store ----
  const float invB = 1.0f / 8192.0f;
  float mean = __hip_atomic_load(&sums[colL], __ATOMIC_RELAXED, __HIP_MEMORY_SCOPE_AGENT) * invB;
  float msq  = __hip_atomic_load(&sums[WIDTH + colL], __ATOMIC_RELAXED, __HIP_MEMORY_SCOPE_AGENT) * invB;
  float rstd = rsqrtf(msq - mean * mean + EPS);
  float g  = gamma[colL];
  float be = beta[colL];
  float wcv = wc[colL];
  int row0 = bm * 128 + ks * 32;
  short* lrow = lastseg + (long)row0 * CIN + colL;
  const float* Rrow = Red + (ks * 32) * 64 + l;  // lanes -> consecutive banks, 2/bank: free
#pragma unroll
  for (int r = 0; r < 32; ++r) {
    float v = Rrow[r * 64];
    float tv = (v - mean) * rstd * g + be;
    tv = tv >= 0.f ? tv : SLOPE * tv;
    tv *= nv[r];
    lrow[(long)r * CIN] = f2bf(tv);
    float p = tv * wcv;
#pragma unroll
    for (int off = 32; off; off >>= 1) p += __shfl_xor(p, off);
    if (l == 0) atomicAdd(&logit[row0 + r], p);
  }
}

// ---------------- sigmoid ----------------------------------------------------
__global__ __launch_bounds__(256) void finalize(const float* __restrict__ logit,
                                                const float* __restrict__ bc,
                                                float* __restrict__ out) {
  int i = blockIdx.x * 256 + threadIdx.x;
  float z = logit[i] + bc[0];
  out[i] = 1.0f / (1.0f + expf(-z));
}

extern "C" void kernel_launch(void* const* d_in, const int* in_sizes, int n_in,
                              void* d_out, int out_size, void* d_ws, size_t ws_size,
                              hipStream_t stream) {
  (void)in_sizes; (void)n_in; (void)out_size; (void)ws_size;
  const float* x     = (const float*)d_in[0];
  WP wp;
  for (int i = 0; i < 7; ++i) wp.p[i] = (const float*)d_in[1 + i];
  // d_in[8] = b (linear bias) — cancels exactly through training-mode BN; unused.
  const float* gamma = (const float*)d_in[9];
  const float* beta  = (const float*)d_in[10];
  const float* Wc    = (const float*)d_in[11];
  const float* bc    = (const float*)d_in[12];
  const float* noise = (const float*)d_in[13];

  char* ws = (char*)d_ws;
  short* lastbf = (short*)ws;                               // 8192*4096 bf16 = 64 MiB
  short* wbf    = (short*)(ws + 67108864 + 16777216);       // 7.34M bf16    = 14 MiB
  float* sums   = (float*)(ws + 67108864 + 16777216 + 14680064);   // 7*1024 f32
  float* logit  = (float*)(ws + 67108864 + 16777216 + 14680064 + 28672);  // 8192 f32
  unsigned* ctr = (unsigned*)(ws + 67108864 + 16777216 + 14680064 + 28672 + 32768);  // 8 u32

  prolog<<<9216, 256, 0, stream>>>(wp, wbf, x, Wc, lastbf, logit, sums, ctr);

  long woff = 0;
  for (int i = 0; i < DEPTH; ++i) {
    int K = 512 * (i + 1);
    layer_fused<<<dim3(64, 8), 256, 0, stream>>>(
        lastbf, wbf + woff, sums + i * 1024,
        gamma + i * 512, beta + i * 512,
        noise + (long)i * B_ROWS * WIDTH,
        Wc + 512 + i * 512,
        lastbf + 512 + (long)i * 512,
        logit, ctr + i, K);
    woff += (long)512 * K;
  }
  finalize<<<32, 256, 0, stream>>>(logit, bc, (float*)d_out);
}

// Round 11
// 277.561 us; speedup vs baseline: 2.7323x; 2.7323x over previous
//
#include <hip/hip_runtime.h>

#define B_ROWS 8192
#define WIDTH  512
#define DEPTH  7
#define CIN    4096
#define EPS    1e-5f
#define SLOPE  0.01f

typedef __attribute__((ext_vector_type(8))) short short8;
typedef __attribute__((ext_vector_type(4))) short short4v;
typedef __attribute__((ext_vector_type(4))) float f32x4;
typedef __attribute__((ext_vector_type(16))) float f32x16;

// round-to-nearest-even f32 -> bf16 bits
__device__ inline short f2bf(float f) {
  unsigned u = __builtin_bit_cast(unsigned, f);
  unsigned r = (u + 0x7FFFu + ((u >> 16) & 1u)) >> 16;
  return (short)r;
}

__device__ inline float bf2f(short b) {
  unsigned u = ((unsigned)(unsigned short)b) << 16;
  return __builtin_bit_cast(float, u);
}

__device__ inline void gl_lds16(const void* g, void* l) {
  __builtin_amdgcn_global_load_lds(
      (const __attribute__((address_space(1))) unsigned*)g,
      (__attribute__((address_space(3))) unsigned*)l, 16, 0, 0);
}

// ------- merged prologue: convw + initx + zero sums, one launch ---------------
// blocks [0,2048): x -> bf16 concat buffer + classifier partial + zero sums
// blocks [2048,9216): 7 fp32 W's -> packed bf16
struct WP { const float* p[7]; };

__global__ __launch_bounds__(256) void prolog(WP wp, short* __restrict__ wbf,
                                              const float* __restrict__ x,
                                              const float* __restrict__ wc,
                                              short* __restrict__ lastbf,
                                              float* __restrict__ logit,
                                              float* __restrict__ sumsz) {
  if (blockIdx.x >= 2048) {
    long e = ((long)(blockIdx.x - 2048) * 256 + threadIdx.x) * 4;
    int layer; long base;
    if      (e < 262144L)  { layer = 0; base = 0; }
    else if (e < 786432L)  { layer = 1; base = 262144L; }
    else if (e < 1572864L) { layer = 2; base = 786432L; }
    else if (e < 2621440L) { layer = 3; base = 1572864L; }
    else if (e < 3932160L) { layer = 4; base = 2621440L; }
    else if (e < 5505024L) { layer = 5; base = 3932160L; }
    else                   { layer = 6; base = 5505024L; }
    f32x4 v = *(const f32x4*)(wp.p[layer] + (e - base));
    short4v o;
    o.x = f2bf(v.x); o.y = f2bf(v.y); o.z = f2bf(v.z); o.w = f2bf(v.w);
    *(short4v*)(wbf + e) = o;
    return;
  }
  int gid = blockIdx.x * 256 + threadIdx.x;
  if (gid < DEPTH * 1024) sumsz[gid] = 0.f;  // zero all layers' stats buffers
  int w = threadIdx.x >> 6, l = threadIdx.x & 63;
  int r = blockIdx.x * 4 + w;
  const float* xr = x + (long)r * 512 + l * 8;
  f32x4 v0 = *(const f32x4*)xr;
  f32x4 v1 = *(const f32x4*)(xr + 4);
  const float* wcr = wc + l * 8;
  float acc = 0.f;
  short8 ob;
#pragma unroll
  for (int j = 0; j < 4; ++j) { acc += v0[j] * wcr[j];     ob[j]     = f2bf(v0[j]); }
#pragma unroll
  for (int j = 0; j < 4; ++j) { acc += v1[j] * wcr[4 + j]; ob[4 + j] = f2bf(v1[j]); }
  *(short8*)&lastbf[(long)r * CIN + l * 8] = ob;
#pragma unroll
  for (int off = 32; off; off >>= 1) acc += __shfl_xor(acc, off);
  if (l == 0) logit[r] = acc;
}

// ---------------- bf16 MFMA GEMM + fused column stats -------------------------
// BM=128, BN=64, BK=64, grid (64,8) = 512 blocks -> 2 blocks/CU.
// __launch_bounds__(256,2): 256-VGPR budget, NO spill (R7's (256,3) forced an
// 84-VGPR allocation and spilled the 128-VGPR accumulator to scratch — never
// cap below the accumulator footprint; HW VGPR steps are 64/128/256).
// 4 waves; wave ks owns the k16 slice ks of each BK=64 tile and covers the
// FULL 128x64 output tile with 32x32x16 MFMA (acc[4][2] f32x16).
// LDS: dbuf x (As 16KB + Bs 8KB), XOR-swizzled (byte ^ ((row&7)<<4)) via
// pre-swizzled global source (both-sides involution, rule #21).
// Epilogue: 4-pass sequential combine in Red (aliases staging LDS), ks=0
// writes C in BF16 and atomically accumulates per-column sum/sumsq (f32).
__global__ __launch_bounds__(256, 2) void gemm_fused(const short* __restrict__ A,
                                                     const short* __restrict__ Bw,
                                                     short* __restrict__ C,
                                                     float* __restrict__ sums,
                                                     int K) {
  __shared__ __align__(16) char smem[49152];  // 2 x (As 16KB + Bs 8KB)
  int t = threadIdx.x;
  int ks = t >> 6, l = t & 63;
  int l31 = l & 31, hi = l >> 5;
  int bm = blockIdx.x, bn = blockIdx.y;
  const short* Ab = A + (long)(bm * 128) * CIN;
  const short* Bb = Bw + (long)(bn * 64) * K;

  f32x16 acc[4][2];
#pragma unroll
  for (int m = 0; m < 4; ++m)
#pragma unroll
    for (int n = 0; n < 2; ++n)
#pragma unroll
      for (int r = 0; r < 16; ++r) acc[m][n][r] = 0.f;

  // staging: 24 x 1KB chunks (A: 16, B: 8); wave ks stages A chunks 4ks..4ks+3
  // and B chunks 2ks..2ks+1. dest row = chunk*8 + (l>>3); source col
  // pre-swizzled so read-side byte^((row&7)<<4) is the matching involution.
  int l8 = l >> 3;
  int scol = ((l & 7) ^ l8) << 3;  // element offset of this lane's 16B chunk

#define STAGE(buf, k0)                                                                       \
  {                                                                                          \
    char* base = smem + (buf) * 24576;                                                       \
    int c0 = ks * 4, c1 = ks * 2;                                                            \
    gl_lds16(Ab + (long)((c0    ) * 8 + l8) * CIN + (k0) + scol, base + (c0    ) * 1024);    \
    gl_lds16(Ab + (long)((c0 + 1) * 8 + l8) * CIN + (k0) + scol, base + (c0 + 1) * 1024);    \
    gl_lds16(Ab + (long)((c0 + 2) * 8 + l8) * CIN + (k0) + scol, base + (c0 + 2) * 1024);    \
    gl_lds16(Ab + (long)((c0 + 3) * 8 + l8) * CIN + (k0) + scol, base + (c0 + 3) * 1024);    \
    gl_lds16(Bb + (long)((c1    ) * 8 + l8) * K + (k0) + scol, base + 16384 + (c1    ) * 1024); \
    gl_lds16(Bb + (long)((c1 + 1) * 8 + l8) * K + (k0) + scol, base + 16384 + (c1 + 1) * 1024); \
  }

  STAGE(0, 0);
  __syncthreads();

  // fragment read offsets: wave ks reads k-bytes [ks*32, ks*32+32) of each
  // 128B row; lane's 16B at kb = ks*32 + hi*16, XOR'd with ((row&7)<<4).
  int kb = ks * 32 + hi * 16;
  int sw = (l & 7) << 4;  // row&7 == l&7 since frag rows are m*32 + l31

  int nt = K >> 6;
  int cur = 0;
  for (int tix = 0; tix < nt; ++tix) {
    if (tix + 1 < nt) STAGE(cur ^ 1, (tix + 1) << 6);
    const char* AsC = smem + cur * 24576;
    const char* BsC = AsC + 16384;
    short8 a[4], b[2];
#pragma unroll
    for (int m = 0; m < 4; ++m)
      a[m] = *(const short8*)(AsC + (m * 32 + l31) * 128 + (kb ^ sw));
#pragma unroll
    for (int n = 0; n < 2; ++n)
      b[n] = *(const short8*)(BsC + (n * 32 + l31) * 128 + (kb ^ sw));
#pragma unroll
    for (int m = 0; m < 4; ++m)
#pragma unroll
      for (int n = 0; n < 2; ++n)
        acc[m][n] = __builtin_amdgcn_mfma_f32_32x32x16_bf16(a[m], b[n], acc[m][n], 0, 0, 0);
    __syncthreads();  // staged buf^1 complete + all reads of cur done
    cur ^= 1;
  }

  // ---- combine 4 K-quarters (Red aliases staging LDS), write bf16 C, stats ----
  float* Red = (float*)smem;  // 128x64 f32 = 32KB
#define RIDX(m, n, r) (((m) * 32 + ((r) & 3) + 8 * ((r) >> 2) + 4 * hi) * 64 + (n) * 32 + l31)
  if (ks == 3) {
#pragma unroll
    for (int m = 0; m < 4; ++m)
#pragma unroll
      for (int n = 0; n < 2; ++n)
#pragma unroll
        for (int r = 0; r < 16; ++r) Red[RIDX(m, n, r)] = acc[m][n][r];
  }
  __syncthreads();
  if (ks == 2) {
#pragma unroll
    for (int m = 0; m < 4; ++m)
#pragma unroll
      for (int n = 0; n < 2; ++n)
#pragma unroll
        for (int r = 0; r < 16; ++r) Red[RIDX(m, n, r)] += acc[m][n][r];
  }
  __syncthreads();
  if (ks == 1) {
#pragma unroll
    for (int m = 0; m < 4; ++m)
#pragma unroll
      for (int n = 0; n < 2; ++n)
#pragma unroll
        for (int r = 0; r < 16; ++r) Red[RIDX(m, n, r)] += acc[m][n][r];
  }
  __syncthreads();
  if (ks == 0) {
    short* Cb = C + (long)(bm * 128) * WIDTH + bn * 64;
#pragma unroll
    for (int n = 0; n < 2; ++n) {
      float s = 0.f, q = 0.f;
#pragma unroll
      for (int m = 0; m < 4; ++m) {
#pragma unroll
        for (int r = 0; r < 16; ++r) {
          int cr = (r & 3) + 8 * (r >> 2) + 4 * hi;
          float v = acc[m][n][r] + Red[RIDX(m, n, r)];
          Cb[(long)(m * 32 + cr) * WIDTH + n * 32 + l31] = f2bf(v);
          s += v; q += v * v;
        }
      }
      s += __shfl_xor(s, 32);
      q += __shfl_xor(q, 32);
      if (l < 32) {
        int colg = bn * 64 + n * 32 + l;
        atomicAdd(&sums[colg], s);
        atomicAdd(&sums[WIDTH + colg], q);
      }
    }
  }
#undef RIDX
#undef STAGE
}

// ---------------- BN + LeakyReLU + noise + classifier partial + bf16 store ----
__global__ __launch_bounds__(256) void bnact(const short* __restrict__ h,
                                             const float* __restrict__ sums,
                                             const float* __restrict__ gamma,
                                             const float* __restrict__ beta,
                                             const float* __restrict__ noise,
                                             const float* __restrict__ wc,
                                             short* __restrict__ lastseg,
                                             float* __restrict__ logit) {
  int w = threadIdx.x >> 6, l = threadIdx.x & 63;
  int r = blockIdx.x * 4 + w;
  int c = l * 8;
  const float invB = 1.0f / 8192.0f;
  short8 hb = *(const short8*)&h[(long)r * WIDTH + c];
  f32x4 n0 = *(const f32x4*)&noise[(long)r * WIDTH + c];
  f32x4 n1 = *(const f32x4*)&noise[(long)r * WIDTH + c + 4];
  float acc = 0.f;
  short8 ob;
#pragma unroll
  for (int j = 0; j < 8; ++j) {
    int cc = c + j;
    float hv = bf2f(hb[j]);
    float nv = j < 4 ? n0[j] : n1[j - 4];
    float mean = sums[cc] * invB;
    float var = sums[WIDTH + cc] * invB - mean * mean;
    float v = (hv - mean) * rsqrtf(var + EPS);
    v = v * gamma[cc] + beta[cc];
    v = v >= 0.f ? v : SLOPE * v;
    v *= nv;
    acc += v * wc[cc];
    ob[j] = f2bf(v);
  }
  *(short8*)&lastseg[(long)r * CIN + c] = ob;
#pragma unroll
  for (int off = 32; off; off >>= 1) acc += __shfl_xor(acc, off);
  if (l == 0) logit[r] += acc;  // one wave per row: no race
}

// ---------------- sigmoid ----------------------------------------------------
__global__ __launch_bounds__(256) void finalize(const float* __restrict__ logit,
                                                const float* __restrict__ bc,
                                                float* __restrict__ out) {
  int i = blockIdx.x * 256 + threadIdx.x;
  float z = logit[i] + bc[0];
  out[i] = 1.0f / (1.0f + expf(-z));
}

extern "C" void kernel_launch(void* const* d_in, const int* in_sizes, int n_in,
                              void* d_out, int out_size, void* d_ws, size_t ws_size,
                              hipStream_t stream) {
  (void)in_sizes; (void)n_in; (void)out_size; (void)ws_size;
  const float* x     = (const float*)d_in[0];
  WP wp;
  for (int i = 0; i < 7; ++i) wp.p[i] = (const float*)d_in[1 + i];
  // d_in[8] = b (linear bias) — cancels exactly through training-mode BN; unused.
  const float* gamma = (const float*)d_in[9];
  const float* beta  = (const float*)d_in[10];
  const float* Wc    = (const float*)d_in[11];
  const float* bc    = (const float*)d_in[12];
  const float* noise = (const float*)d_in[13];

  char* ws = (char*)d_ws;
  short* lastbf = (short*)ws;                               // 8192*4096 bf16 = 64 MiB
  short* hpre   = (short*)(ws + 67108864);                  // 8192*512 bf16 = 8 MiB
  short* wbf    = (short*)(ws + 67108864 + 16777216);       // 7.34M bf16    = 14 MiB
  float* sums   = (float*)(ws + 67108864 + 16777216 + 14680064);   // 7*1024 f32
  float* logit  = (float*)(ws + 67108864 + 16777216 + 14680064 + 28672);  // 8192 f32

  prolog<<<9216, 256, 0, stream>>>(wp, wbf, x, Wc, lastbf, logit, sums);

  long woff = 0;
  for (int i = 0; i < DEPTH; ++i) {
    int K = 512 * (i + 1);
    gemm_fused<<<dim3(64, 8), 256, 0, stream>>>(lastbf, wbf + woff, hpre,
                                                sums + i * 1024, K);
    bnact<<<2048, 256, 0, stream>>>(hpre, sums + i * 1024,
                                    gamma + i * 512, beta + i * 512,
                                    noise + (long)i * B_ROWS * WIDTH,
                                    Wc + 512 + i * 512,
                                    lastbf + 512 + (long)i * 512, logit);
    woff += (long)512 * K;
  }
  finalize<<<32, 256, 0, stream>>>(logit, bc, (float*)d_out);
}

// Round 12
// 273.395 us; speedup vs baseline: 2.7739x; 1.0152x over previous
//
#include <hip/hip_runtime.h>

#define B_ROWS 8192
#define WIDTH  512
#define DEPTH  7
#define CIN    4096
#define EPS    1e-5f
#define SLOPE  0.01f

typedef __attribute__((ext_vector_type(8))) short short8;
typedef __attribute__((ext_vector_type(4))) short short4v;
typedef __attribute__((ext_vector_type(4))) float f32x4;
typedef __attribute__((ext_vector_type(16))) float f32x16;

// round-to-nearest-even f32 -> bf16 bits
__device__ inline short f2bf(float f) {
  unsigned u = __builtin_bit_cast(unsigned, f);
  unsigned r = (u + 0x7FFFu + ((u >> 16) & 1u)) >> 16;
  return (short)r;
}

__device__ inline float bf2f(short b) {
  unsigned u = ((unsigned)(unsigned short)b) << 16;
  return __builtin_bit_cast(float, u);
}

__device__ inline void gl_lds16(const void* g, void* l) {
  __builtin_amdgcn_global_load_lds(
      (const __attribute__((address_space(1))) unsigned*)g,
      (__attribute__((address_space(3))) unsigned*)l, 16, 0, 0);
}

// ------- merged prologue: convw (8 elems/thread) + initx + zero sums ----------
// blocks [0,2048): x -> bf16 concat buffer + classifier partial + zero sums
// blocks [2048,5632): 7 fp32 W's -> packed bf16 (8 elems/thread)
struct WP { const float* p[7]; };

__global__ __launch_bounds__(256) void prolog(WP wp, short* __restrict__ wbf,
                                              const float* __restrict__ x,
                                              const float* __restrict__ wc,
                                              short* __restrict__ lastbf,
                                              float* __restrict__ logit,
                                              float* __restrict__ sumsz) {
  if (blockIdx.x >= 2048) {
    long e = ((long)(blockIdx.x - 2048) * 256 + threadIdx.x) * 8;
    int layer; long base;
    if      (e < 262144L)  { layer = 0; base = 0; }
    else if (e < 786432L)  { layer = 1; base = 262144L; }
    else if (e < 1572864L) { layer = 2; base = 786432L; }
    else if (e < 2621440L) { layer = 3; base = 1572864L; }
    else if (e < 3932160L) { layer = 4; base = 2621440L; }
    else if (e < 5505024L) { layer = 5; base = 3932160L; }
    else                   { layer = 6; base = 5505024L; }
    const float* src = wp.p[layer] + (e - base);
    f32x4 v0 = *(const f32x4*)src;
    f32x4 v1 = *(const f32x4*)(src + 4);
    short8 o;
    o[0] = f2bf(v0.x); o[1] = f2bf(v0.y); o[2] = f2bf(v0.z); o[3] = f2bf(v0.w);
    o[4] = f2bf(v1.x); o[5] = f2bf(v1.y); o[6] = f2bf(v1.z); o[7] = f2bf(v1.w);
    *(short8*)(wbf + e) = o;
    return;
  }
  int gid = blockIdx.x * 256 + threadIdx.x;
  if (gid < DEPTH * 1024) sumsz[gid] = 0.f;  // zero all layers' stats buffers
  int w = threadIdx.x >> 6, l = threadIdx.x & 63;
  int r = blockIdx.x * 4 + w;
  const float* xr = x + (long)r * 512 + l * 8;
  f32x4 v0 = *(const f32x4*)xr;
  f32x4 v1 = *(const f32x4*)(xr + 4);
  const float* wcr = wc + l * 8;
  float acc = 0.f;
  short8 ob;
#pragma unroll
  for (int j = 0; j < 4; ++j) { acc += v0[j] * wcr[j];     ob[j]     = f2bf(v0[j]); }
#pragma unroll
  for (int j = 0; j < 4; ++j) { acc += v1[j] * wcr[4 + j]; ob[4 + j] = f2bf(v1[j]); }
  *(short8*)&lastbf[(long)r * CIN + l * 8] = ob;
#pragma unroll
  for (int off = 32; off; off >>= 1) acc += __shfl_xor(acc, off);
  if (l == 0) logit[r] = acc;
}

// ---------------- bf16 MFMA GEMM + fused column stats -------------------------
// BM=128, BN=64, BK=64, grid (64,8) = 512 blocks -> 2 blocks/CU.
// __launch_bounds__(256,2): 256-VGPR budget, NO spill (R7's (256,3) forced an
// 84-VGPR allocation and spilled the 128-VGPR accumulator to scratch — never
// cap below the accumulator footprint; HW VGPR steps are 64/128/256).
// 4 waves; wave ks owns the k16 slice ks of each BK=64 tile and covers the
// FULL 128x64 output tile with 32x32x16 MFMA (acc[4][2] f32x16).
// LDS: dbuf x (As 16KB + Bs 8KB), XOR-swizzled (byte ^ ((row&7)<<4)) via
// pre-swizzled global source (both-sides involution, rule #21).
// Epilogue: 4-pass sequential combine in Red (aliases staging LDS), ks=0
// writes C in BF16 and atomically accumulates per-column sum/sumsq (f32).
__global__ __launch_bounds__(256, 2) void gemm_fused(const short* __restrict__ A,
                                                     const short* __restrict__ Bw,
                                                     short* __restrict__ C,
                                                     float* __restrict__ sums,
                                                     int K) {
  __shared__ __align__(16) char smem[49152];  // 2 x (As 16KB + Bs 8KB)
  int t = threadIdx.x;
  int ks = t >> 6, l = t & 63;
  int l31 = l & 31, hi = l >> 5;
  int bm = blockIdx.x, bn = blockIdx.y;
  const short* Ab = A + (long)(bm * 128) * CIN;
  const short* Bb = Bw + (long)(bn * 64) * K;

  f32x16 acc[4][2];
#pragma unroll
  for (int m = 0; m < 4; ++m)
#pragma unroll
    for (int n = 0; n < 2; ++n)
#pragma unroll
      for (int r = 0; r < 16; ++r) acc[m][n][r] = 0.f;

  // staging: 24 x 1KB chunks (A: 16, B: 8); wave ks stages A chunks 4ks..4ks+3
  // and B chunks 2ks..2ks+1. dest row = chunk*8 + (l>>3); source col
  // pre-swizzled so read-side byte^((row&7)<<4) is the matching involution.
  int l8 = l >> 3;
  int scol = ((l & 7) ^ l8) << 3;  // element offset of this lane's 16B chunk

#define STAGE(buf, k0)                                                                       \
  {                                                                                          \
    char* base = smem + (buf) * 24576;                                                       \
    int c0 = ks * 4, c1 = ks * 2;                                                            \
    gl_lds16(Ab + (long)((c0    ) * 8 + l8) * CIN + (k0) + scol, base + (c0    ) * 1024);    \
    gl_lds16(Ab + (long)((c0 + 1) * 8 + l8) * CIN + (k0) + scol, base + (c0 + 1) * 1024);    \
    gl_lds16(Ab + (long)((c0 + 2) * 8 + l8) * CIN + (k0) + scol, base + (c0 + 2) * 1024);    \
    gl_lds16(Ab + (long)((c0 + 3) * 8 + l8) * CIN + (k0) + scol, base + (c0 + 3) * 1024);    \
    gl_lds16(Bb + (long)((c1    ) * 8 + l8) * K + (k0) + scol, base + 16384 + (c1    ) * 1024); \
    gl_lds16(Bb + (long)((c1 + 1) * 8 + l8) * K + (k0) + scol, base + 16384 + (c1 + 1) * 1024); \
  }

  STAGE(0, 0);
  __syncthreads();

  // fragment read offsets: wave ks reads k-bytes [ks*32, ks*32+32) of each
  // 128B row; lane's 16B at kb = ks*32 + hi*16, XOR'd with ((row&7)<<4).
  int kb = ks * 32 + hi * 16;
  int sw = (l & 7) << 4;  // row&7 == l&7 since frag rows are m*32 + l31

  int nt = K >> 6;
  int cur = 0;
  for (int tix = 0; tix < nt; ++tix) {
    if (tix + 1 < nt) STAGE(cur ^ 1, (tix + 1) << 6);
    const char* AsC = smem + cur * 24576;
    const char* BsC = AsC + 16384;
    short8 a[4], b[2];
#pragma unroll
    for (int m = 0; m < 4; ++m)
      a[m] = *(const short8*)(AsC + (m * 32 + l31) * 128 + (kb ^ sw));
#pragma unroll
    for (int n = 0; n < 2; ++n)
      b[n] = *(const short8*)(BsC + (n * 32 + l31) * 128 + (kb ^ sw));
#pragma unroll
    for (int m = 0; m < 4; ++m)
#pragma unroll
      for (int n = 0; n < 2; ++n)
        acc[m][n] = __builtin_amdgcn_mfma_f32_32x32x16_bf16(a[m], b[n], acc[m][n], 0, 0, 0);
    __syncthreads();  // staged buf^1 complete + all reads of cur done
    cur ^= 1;
  }

  // ---- combine 4 K-quarters (Red aliases staging LDS), write bf16 C, stats ----
  float* Red = (float*)smem;  // 128x64 f32 = 32KB
#define RIDX(m, n, r) (((m) * 32 + ((r) & 3) + 8 * ((r) >> 2) + 4 * hi) * 64 + (n) * 32 + l31)
  if (ks == 3) {
#pragma unroll
    for (int m = 0; m < 4; ++m)
#pragma unroll
      for (int n = 0; n < 2; ++n)
#pragma unroll
        for (int r = 0; r < 16; ++r) Red[RIDX(m, n, r)] = acc[m][n][r];
  }
  __syncthreads();
  if (ks == 2) {
#pragma unroll
    for (int m = 0; m < 4; ++m)
#pragma unroll
      for (int n = 0; n < 2; ++n)
#pragma unroll
        for (int r = 0; r < 16; ++r) Red[RIDX(m, n, r)] += acc[m][n][r];
  }
  __syncthreads();
  if (ks == 1) {
#pragma unroll
    for (int m = 0; m < 4; ++m)
#pragma unroll
      for (int n = 0; n < 2; ++n)
#pragma unroll
        for (int r = 0; r < 16; ++r) Red[RIDX(m, n, r)] += acc[m][n][r];
  }
  __syncthreads();
  if (ks == 0) {
    short* Cb = C + (long)(bm * 128) * WIDTH + bn * 64;
#pragma unroll
    for (int n = 0; n < 2; ++n) {
      float s = 0.f, q = 0.f;
#pragma unroll
      for (int m = 0; m < 4; ++m) {
#pragma unroll
        for (int r = 0; r < 16; ++r) {
          int cr = (r & 3) + 8 * (r >> 2) + 4 * hi;
          float v = acc[m][n][r] + Red[RIDX(m, n, r)];
          Cb[(long)(m * 32 + cr) * WIDTH + n * 32 + l31] = f2bf(v);
          s += v; q += v * v;
        }
      }
      s += __shfl_xor(s, 32);
      q += __shfl_xor(q, 32);
      if (l < 32) {
        int colg = bn * 64 + n * 32 + l;
        atomicAdd(&sums[colg], s);
        atomicAdd(&sums[WIDTH + colg], q);
      }
    }
  }
#undef RIDX
#undef STAGE
}

// ---------------- BN + LeakyReLU + noise + classifier partial + bf16 store ----
__global__ __launch_bounds__(256) void bnact(const short* __restrict__ h,
                                             const float* __restrict__ sums,
                                             const float* __restrict__ gamma,
                                             const float* __restrict__ beta,
                                             const float* __restrict__ noise,
                                             const float* __restrict__ wc,
                                             short* __restrict__ lastseg,
                                             float* __restrict__ logit) {
  int w = threadIdx.x >> 6, l = threadIdx.x & 63;
  int r = blockIdx.x * 4 + w;
  int c = l * 8;
  const float invB = 1.0f / 8192.0f;
  short8 hb = *(const short8*)&h[(long)r * WIDTH + c];
  f32x4 n0 = *(const f32x4*)&noise[(long)r * WIDTH + c];
  f32x4 n1 = *(const f32x4*)&noise[(long)r * WIDTH + c + 4];
  float acc = 0.f;
  short8 ob;
#pragma unroll
  for (int j = 0; j < 8; ++j) {
    int cc = c + j;
    float hv = bf2f(hb[j]);
    float nv = j < 4 ? n0[j] : n1[j - 4];
    float mean = sums[cc] * invB;
    float var = sums[WIDTH + cc] * invB - mean * mean;
    float v = (hv - mean) * rsqrtf(var + EPS);
    v = v * gamma[cc] + beta[cc];
    v = v >= 0.f ? v : SLOPE * v;
    v *= nv;
    acc += v * wc[cc];
    ob[j] = f2bf(v);
  }
  *(short8*)&lastseg[(long)r * CIN + c] = ob;
#pragma unroll
  for (int off = 32; off; off >>= 1) acc += __shfl_xor(acc, off);
  if (l == 0) logit[r] += acc;  // one wave per row: no race
}

// ---- last layer: BN + act + classifier partial + sigmoid straight to out ----
// Layer 6's concat segment is never read again, so no lastbf store; lane 0
// holds the completed logit (x + layers 0..5 from `logit`, layer 6 from acc).
__global__ __launch_bounds__(256) void bnact_last(const short* __restrict__ h,
                                                  const float* __restrict__ sums,
                                                  const float* __restrict__ gamma,
                                                  const float* __restrict__ beta,
                                                  const float* __restrict__ noise,
                                                  const float* __restrict__ wc,
                                                  const float* __restrict__ logit,
                                                  const float* __restrict__ bc,
                                                  float* __restrict__ out) {
  int w = threadIdx.x >> 6, l = threadIdx.x & 63;
  int r = blockIdx.x * 4 + w;
  int c = l * 8;
  const float invB = 1.0f / 8192.0f;
  short8 hb = *(const short8*)&h[(long)r * WIDTH + c];
  f32x4 n0 = *(const f32x4*)&noise[(long)r * WIDTH + c];
  f32x4 n1 = *(const f32x4*)&noise[(long)r * WIDTH + c + 4];
  float acc = 0.f;
#pragma unroll
  for (int j = 0; j < 8; ++j) {
    int cc = c + j;
    float hv = bf2f(hb[j]);
    float nv = j < 4 ? n0[j] : n1[j - 4];
    float mean = sums[cc] * invB;
    float var = sums[WIDTH + cc] * invB - mean * mean;
    float v = (hv - mean) * rsqrtf(var + EPS);
    v = v * gamma[cc] + beta[cc];
    v = v >= 0.f ? v : SLOPE * v;
    v *= nv;
    acc += v * wc[cc];
  }
#pragma unroll
  for (int off = 32; off; off >>= 1) acc += __shfl_xor(acc, off);
  if (l == 0) {
    float z = logit[r] + acc + bc[0];
    out[r] = 1.0f / (1.0f + expf(-z));
  }
}

extern "C" void kernel_launch(void* const* d_in, const int* in_sizes, int n_in,
                              void* d_out, int out_size, void* d_ws, size_t ws_size,
                              hipStream_t stream) {
  (void)in_sizes; (void)n_in; (void)out_size; (void)ws_size;
  const float* x     = (const float*)d_in[0];
  WP wp;
  for (int i = 0; i < 7; ++i) wp.p[i] = (const float*)d_in[1 + i];
  // d_in[8] = b (linear bias) — cancels exactly through training-mode BN; unused.
  const float* gamma = (const float*)d_in[9];
  const float* beta  = (const float*)d_in[10];
  const float* Wc    = (const float*)d_in[11];
  const float* bc    = (const float*)d_in[12];
  const float* noise = (const float*)d_in[13];

  char* ws = (char*)d_ws;
  short* lastbf = (short*)ws;                               // 8192*4096 bf16 = 64 MiB
  short* hpre   = (short*)(ws + 67108864);                  // 8192*512 bf16 = 8 MiB
  short* wbf    = (short*)(ws + 67108864 + 16777216);       // 7.34M bf16    = 14 MiB
  float* sums   = (float*)(ws + 67108864 + 16777216 + 14680064);   // 7*1024 f32
  float* logit  = (float*)(ws + 67108864 + 16777216 + 14680064 + 28672);  // 8192 f32

  prolog<<<5632, 256, 0, stream>>>(wp, wbf, x, Wc, lastbf, logit, sums);

  long woff = 0;
  for (int i = 0; i < DEPTH; ++i) {
    int K = 512 * (i + 1);
    gemm_fused<<<dim3(64, 8), 256, 0, stream>>>(lastbf, wbf + woff, hpre,
                                                sums + i * 1024, K);
    if (i < DEPTH - 1) {
      bnact<<<2048, 256, 0, stream>>>(hpre, sums + i * 1024,
                                      gamma + i * 512, beta + i * 512,
                                      noise + (long)i * B_ROWS * WIDTH,
                                      Wc + 512 + i * 512,
                                      lastbf + 512 + (long)i * 512, logit);
    } else {
      bnact_last<<<2048, 256, 0, stream>>>(hpre, sums + i * 1024,
                                           gamma + i * 512, beta + i * 512,
                                           noise + (long)i * B_ROWS * WIDTH,
                                           Wc + 512 + i * 512,
                                           logit, bc, (float*)d_out);
    }
    woff += (long)512 * K;
  }
}